// Round 5
// baseline (378.235 us; speedup 1.0000x reference)
//
#include <hip/hip_runtime.h>

#define TEMP    0.5f
#define LOG2E   1.4426950408889634f
#define C2      (LOG2E / TEMP)        /* t = dot * C2 */
#define MSHIFT  160.0f                /* fixed base-2 softmax shift */
#define LN2     0.6931471805599453f
#define NROWS   16384
#define BHALF   8192
#define DDIM    128
#define PREPB   2048                  /* k_prep blocks = 524288/256 */
#define MAINB   1024                  /* k_main grid: 64 rb x 16 cc */

typedef __bf16 bf16x8 __attribute__((ext_vector_type(8)));
typedef float  f32x16 __attribute__((ext_vector_type(16)));

__device__ __forceinline__ float fexp2(float x) {
#if __has_builtin(__builtin_amdgcn_exp2f)
  return __builtin_amdgcn_exp2f(x);
#else
  return exp2f(x);
#endif
}

__device__ __forceinline__ unsigned short f2bf(float f) {
  unsigned int u = __float_as_uint(f);
  unsigned int r = (u + 0x7FFFu + ((u >> 16) & 1u)) >> 16;  // RNE
  return (unsigned short)r;
}

// ---------------------------------------------------------------------------
// zbF frag-major layout: row r, k-index k:
//   g = r/32, lo = r%32, khi = k/8, j = k%8
//   short index = g*4096 + khi*256 + lo*8 + j
// A wave's frag load (fixed khi): 64 lanes read a contiguous 1KB block.
// ---------------------------------------------------------------------------

__global__ void k_prep(const float* __restrict__ zi, const float* __restrict__ zj,
                       unsigned short* __restrict__ zbF,
                       float* __restrict__ S, float* __restrict__ Pp,
                       unsigned int* __restrict__ Cnt) {
  const int t   = blockIdx.x * 256 + threadIdx.x;   // 0..524287 float4 groups
  const int row = t >> 5;                           // 32 float4 per 128-elt row
  const int k0  = (t & 31) * 4;
  const float* src = (row < BHALF) ? (zi + (size_t)row * DDIM)
                                   : (zj + (size_t)(row - BHALF) * DDIM);
  float4 v = *reinterpret_cast<const float4*>(src + k0);

  const int g = row >> 5, lo = row & 31, khi = k0 >> 3, j0 = k0 & 7;
  ushort4 o;
  o.x = f2bf(v.x); o.y = f2bf(v.y); o.z = f2bf(v.z); o.w = f2bf(v.w);
  *reinterpret_cast<ushort4*>(zbF + (size_t)g * 4096 + khi * 256 + lo * 8 + j0) = o;

  float dot = 0.f;
  if (row < BHALF) {
    float4 w = *reinterpret_cast<const float4*>(zj + (size_t)row * DDIM + k0);
    dot = fmaf(v.x, w.x, fmaf(v.y, w.y, fmaf(v.z, w.z, v.w * w.w)));
  }
#pragma unroll
  for (int m = 32; m >= 1; m >>= 1) dot += __shfl_xor(dot, m, 64);
  __shared__ float red[4];
  if ((threadIdx.x & 63) == 0) red[threadIdx.x >> 6] = dot;
  __syncthreads();
  if (threadIdx.x == 0) Pp[blockIdx.x] = red[0] + red[1] + red[2] + red[3];

  if (t < NROWS) S[t] = 0.f;
  if (t == 0)    *Cnt = 0u;
}

// ---------------------------------------------------------------------------
// k_main: 64 persistent rows/wave (MFMA B operand, 2 row-tiles of 32), streams
// 32-col tiles as A from frag-major zbF. Minimal register footprint
// (~124 regs) so 4 waves/SIMD provide the latency hiding (TLP, not ILP).
// Last block finalizes the loss.
// ---------------------------------------------------------------------------
__device__ __forceinline__ void loadA(bf16x8 (&a)[8], const unsigned short* ap) {
#pragma unroll
  for (int ks = 0; ks < 8; ++ks)
    a[ks] = *reinterpret_cast<const bf16x8*>(ap + ks * 512);
}

__device__ __forceinline__ f32x16 chain8(const bf16x8 (&a)[8], const bf16x8 (&b)[8]) {
  f32x16 z = {};
  f32x16 o = __builtin_amdgcn_mfma_f32_32x32x16_bf16(a[0], b[0], z, 0, 0, 0);
#pragma unroll
  for (int ks = 1; ks < 8; ++ks)
    o = __builtin_amdgcn_mfma_f32_32x32x16_bf16(a[ks], b[ks], o, 0, 0, 0);
  return o;
}

template <bool MK>
__device__ __forceinline__ void exp16(const f32x16& A, float& s, int d, int hi) {
  float t0 = 0.f, t1 = 0.f;
#pragma unroll
  for (int r = 0; r < 16; ++r) {
    float e = fexp2(fmaf(A[r], C2, -MSHIFT));
    if (MK) {
      const int rloc = (r & 3) + 8 * (r >> 2) + 4 * hi;  // C/D reg map (verified)
      if (rloc == d) e = 0.f;
    }
    if (r & 1) t1 += e; else t0 += e;
  }
  s += t0 + t1;
}

__global__ __launch_bounds__(256, 4)
void k_main(const unsigned short* __restrict__ zbF, float* __restrict__ S,
            const float* __restrict__ Pp, unsigned int* __restrict__ Cnt,
            float* __restrict__ out) {
  const int wave = threadIdx.x >> 6;
  const int lane = threadIdx.x & 63;
  const int lo = lane & 31;
  const int hi = lane >> 5;
  const int rb = blockIdx.x & 63;       // 64 row blocks of 256 rows
  const int cc = blockIdx.x >> 6;       // 16 col chunks of 1024 cols
  const int row0w = rb * 256 + wave * 64;

  // persistent row frags (B operand): 2 row-tiles x 8 k-steps = 64 regs
  bf16x8 b0[8], b1[8];
  loadA(b0, zbF + (size_t)(row0w >> 5)       * 4096 + hi * 256 + lo * 8);
  loadA(b1, zbF + (size_t)((row0w >> 5) + 1) * 4096 + hi * 256 + lo * 8);

  float s0 = 0.f, s1 = 0.f;

  const int c0base = cc * 1024;
  const unsigned short* abase = zbF + (size_t)(c0base >> 5) * 4096 + hi * 256 + lo * 8;

  bf16x8 a[8];
  loadA(a, abase);

  for (int it = 0; it < 32; ++it) {
    const int dr = c0base + it * 32 - row0w;   // 0 -> rt0 diag, 32 -> rt1 diag
    f32x16 acc = chain8(a, b0);
    if ((unsigned)dr < 64u) {
      exp16<true>(acc, s0, dr == 0 ? lo : -1, hi);
      acc = chain8(a, b1);
      if (it + 1 < 32) loadA(a, abase + (size_t)(it + 1) * 4096);
      exp16<true>(acc, s1, dr == 32 ? lo : -1, hi);
    } else {
      exp16<false>(acc, s0, -1, hi);
      acc = chain8(a, b1);
      if (it + 1 < 32) loadA(a, abase + (size_t)(it + 1) * 4096);
      exp16<false>(acc, s1, -1, hi);
    }
  }

  // row sums: fold hi halves, one atomic per row per col-chunk
  s0 += __shfl_xor(s0, 32, 64);
  s1 += __shfl_xor(s1, 32, 64);
  if (hi == 0) {
    atomicAdd(&S[row0w + lo],      s0);
    atomicAdd(&S[row0w + 32 + lo], s1);
  }

  // ---- fused finalize: last block computes the loss ----
  __threadfence();
  __shared__ bool isLast;
  if (threadIdx.x == 0)
    isLast = (atomicAdd(Cnt, 1u) == MAINB - 1);
  __syncthreads();
  if (!isLast) return;
  __threadfence();

  const int t = threadIdx.x;
  float q = 0.f;
  for (int r = t; r < NROWS; r += 256) {
    float sv = __hip_atomic_load(&S[r], __ATOMIC_RELAXED, __HIP_MEMORY_SCOPE_AGENT);
    q += LN2 * (MSHIFT + __log2f(sv));
  }
  for (int r = t; r < PREPB; r += 256)
    q -= 4.0f * Pp[r];
  __shared__ float red[256];
  red[t] = q;
  __syncthreads();
  for (int s2 = 128; s2 > 0; s2 >>= 1) {
    if (t < s2) red[t] += red[t + s2];
    __syncthreads();
  }
  if (t == 0) out[0] = red[0] / (float)NROWS;
}

// ---------------------------------------------------------------------------
extern "C" void kernel_launch(void* const* d_in, const int* in_sizes, int n_in,
                              void* d_out, int out_size, void* d_ws, size_t ws_size,
                              hipStream_t stream) {
  const float* zi = (const float*)d_in[0];
  const float* zj = (const float*)d_in[1];
  unsigned short* zbF = (unsigned short*)d_ws;                     // 4 MB
  float* S  = (float*)((char*)d_ws + (size_t)NROWS * DDIM * 2);    // 64 KB
  float* Pp = S + NROWS;                                           // 8 KB
  unsigned int* Cnt = (unsigned int*)(Pp + PREPB);                 // 4 B
  float* out = (float*)d_out;

  hipLaunchKernelGGL(k_prep, dim3(PREPB), dim3(256), 0, stream, zi, zj, zbF, S, Pp, Cnt);
  hipLaunchKernelGGL(k_main, dim3(MAINB), dim3(256), 0, stream, zbF, S, Pp, Cnt, out);
}

// Round 6
// 169.067 us; speedup vs baseline: 2.2372x; 2.2372x over previous
//
#include <hip/hip_runtime.h>

#define TEMP    0.5f
#define LOG2E   1.4426950408889634f
#define C2      (LOG2E / TEMP)        /* t = dot * C2 */
#define MSHIFT  160.0f                /* fixed base-2 softmax shift */
#define LN2     0.6931471805599453f
#define NROWS   16384
#define BHALF   8192
#define DDIM    128
#define PREPB   2048                  /* k_prep blocks = 524288/256 */
#define MAINB   512                   /* k_main grid: 64 rb x 8 cc */

typedef __bf16 bf16x8 __attribute__((ext_vector_type(8)));
typedef float  f32x16 __attribute__((ext_vector_type(16)));

__device__ __forceinline__ float fexp2(float x) {
#if __has_builtin(__builtin_amdgcn_exp2f)
  return __builtin_amdgcn_exp2f(x);
#else
  return exp2f(x);
#endif
}

__device__ __forceinline__ unsigned short f2bf(float f) {
  unsigned int u = __float_as_uint(f);
  unsigned int r = (u + 0x7FFFu + ((u >> 16) & 1u)) >> 16;  // RNE
  return (unsigned short)r;
}

// ---------------------------------------------------------------------------
// zbF frag-major layout: row r, k-index k:
//   g = r/32, lo = r%32, khi = k/8, j = k%8
//   short index = g*4096 + khi*256 + lo*8 + j
// A wave's frag load (fixed khi): 64 lanes read a contiguous 1KB block.
// ---------------------------------------------------------------------------

__global__ void k_prep(const float* __restrict__ zi, const float* __restrict__ zj,
                       unsigned short* __restrict__ zbF,
                       float* __restrict__ S, float* __restrict__ Pp,
                       unsigned int* __restrict__ Cnt) {
  const int t   = blockIdx.x * 256 + threadIdx.x;   // 0..524287 float4 groups
  const int row = t >> 5;                           // 32 float4 per 128-elt row
  const int k0  = (t & 31) * 4;
  const float* src = (row < BHALF) ? (zi + (size_t)row * DDIM)
                                   : (zj + (size_t)(row - BHALF) * DDIM);
  float4 v = *reinterpret_cast<const float4*>(src + k0);

  const int g = row >> 5, lo = row & 31, khi = k0 >> 3, j0 = k0 & 7;
  ushort4 o;
  o.x = f2bf(v.x); o.y = f2bf(v.y); o.z = f2bf(v.z); o.w = f2bf(v.w);
  *reinterpret_cast<ushort4*>(zbF + (size_t)g * 4096 + khi * 256 + lo * 8 + j0) = o;

  float dot = 0.f;
  if (row < BHALF) {
    float4 w = *reinterpret_cast<const float4*>(zj + (size_t)row * DDIM + k0);
    dot = fmaf(v.x, w.x, fmaf(v.y, w.y, fmaf(v.z, w.z, v.w * w.w)));
  }
#pragma unroll
  for (int m = 32; m >= 1; m >>= 1) dot += __shfl_xor(dot, m, 64);
  __shared__ float red[4];
  if ((threadIdx.x & 63) == 0) red[threadIdx.x >> 6] = dot;
  __syncthreads();
  if (threadIdx.x == 0) Pp[blockIdx.x] = red[0] + red[1] + red[2] + red[3];

  if (t < NROWS) S[t] = 0.f;
  if (t == 0)    *Cnt = 0u;
}

// ---------------------------------------------------------------------------
// k_main: 64 persistent rows/wave (MFMA B operand, 2 row-tiles), streams
// 32-col tiles as A. Depth-1 phase pipeline with TWO f32x16 accumulators
// (A0/A1 ping-pong): exp of phase p-1 issues under phase p's independent
// 8-MFMA chain. ~170 live regs -> fits 2 waves/SIMD (256-reg budget),
// the proven spill-free zone. Last block finalizes the loss.
// ---------------------------------------------------------------------------
__device__ __forceinline__ void loadA(bf16x8 (&a)[8], const unsigned short* ap) {
#pragma unroll
  for (int ks = 0; ks < 8; ++ks)
    a[ks] = *reinterpret_cast<const bf16x8*>(ap + ks * 512);
}

__device__ __forceinline__ f32x16 chain8(const bf16x8 (&a)[8], const bf16x8 (&b)[8],
                                         const f32x16& z) {
  f32x16 o = __builtin_amdgcn_mfma_f32_32x32x16_bf16(a[0], b[0], z, 0, 0, 0);
#pragma unroll
  for (int ks = 1; ks < 8; ++ks)
    o = __builtin_amdgcn_mfma_f32_32x32x16_bf16(a[ks], b[ks], o, 0, 0, 0);
  return o;
}

template <bool MK>
__device__ __forceinline__ void exp16(const f32x16& A, float& s, int d, int hi) {
  float t0 = 0.f, t1 = 0.f;
#pragma unroll
  for (int r = 0; r < 16; ++r) {
    float e = fexp2(fmaf(A[r], C2, -MSHIFT));
    if (MK) {
      const int rloc = (r & 3) + 8 * (r >> 2) + 4 * hi;  // C/D reg map (verified)
      if (rloc == d) e = 0.f;
    }
    if (r & 1) t1 += e; else t0 += e;
  }
  s += t0 + t1;
}

__global__ __launch_bounds__(256, 2)
void k_main(const unsigned short* __restrict__ zbF, float* __restrict__ S,
            const float* __restrict__ Pp, unsigned int* __restrict__ Cnt,
            float* __restrict__ out) {
  const int wave = threadIdx.x >> 6;
  const int lane = threadIdx.x & 63;
  const int lo = lane & 31;
  const int hi = lane >> 5;
  const int rb = blockIdx.x & 63;       // 64 row blocks of 256 rows
  const int cc = blockIdx.x >> 6;       // 8 col chunks of 2048 cols
  const int row0w = rb * 256 + wave * 64;

  // persistent row frags (B operand): 2 row-tiles x 8 k-steps = 64 regs
  bf16x8 b0[8], b1[8];
  loadA(b0, zbF + (size_t)(row0w >> 5)       * 4096 + hi * 256 + lo * 8);
  loadA(b1, zbF + (size_t)((row0w >> 5) + 1) * 4096 + hi * 256 + lo * 8);

  float s0 = 0.f, s1 = 0.f;
  const f32x16 kZ = {};

  const int c0base = cc * 2048;
  const unsigned short* abase = zbF + (size_t)(c0base >> 5) * 4096 + hi * 256 + lo * 8;

  bf16x8 a[8];
  loadA(a, abase);

  f32x16 A0 = chain8(a, b0, kZ);        // tile 0, ph0
  f32x16 A1;

  for (int it = 0; it < 64; ++it) {
    const int dr = c0base + it * 32 - row0w;   // 0 -> rt0 diag, 32 -> rt1 diag
    const bool last = (it == 63);

    A1 = chain8(a, b1, kZ);                    // ph1 (a still live here)
    if (!last) loadA(a, abase + (size_t)(it + 1) * 4096);  // WAR-safe reload

    if (dr == 0 || dr == 32) {
      exp16<true>(A0, s0, dr == 0 ? lo : -1, hi);          // under A1's chain
      if (!last) A0 = chain8(a, b0, kZ);                   // next ph0
      exp16<true>(A1, s1, dr == 32 ? lo : -1, hi);         // under A0's chain
    } else {
      exp16<false>(A0, s0, -1, hi);
      if (!last) A0 = chain8(a, b0, kZ);
      exp16<false>(A1, s1, -1, hi);
    }
  }

  // row sums: fold hi halves, one atomic per row per col-chunk
  s0 += __shfl_xor(s0, 32, 64);
  s1 += __shfl_xor(s1, 32, 64);
  if (hi == 0) {
    atomicAdd(&S[row0w + lo],      s0);
    atomicAdd(&S[row0w + 32 + lo], s1);
  }

  // ---- fused finalize: last block computes the loss ----
  __threadfence();
  __shared__ bool isLast;
  if (threadIdx.x == 0)
    isLast = (atomicAdd(Cnt, 1u) == MAINB - 1);
  __syncthreads();
  if (!isLast) return;
  __threadfence();

  const int t = threadIdx.x;
  float q = 0.f;
  for (int r = t; r < NROWS; r += 256) {
    float sv = __hip_atomic_load(&S[r], __ATOMIC_RELAXED, __HIP_MEMORY_SCOPE_AGENT);
    q += LN2 * (MSHIFT + __log2f(sv));
  }
  for (int r = t; r < PREPB; r += 256)
    q -= 4.0f * Pp[r];
  __shared__ float red[256];
  red[t] = q;
  __syncthreads();
  for (int s2 = 128; s2 > 0; s2 >>= 1) {
    if (t < s2) red[t] += red[t + s2];
    __syncthreads();
  }
  if (t == 0) out[0] = red[0] / (float)NROWS;
}

// ---------------------------------------------------------------------------
extern "C" void kernel_launch(void* const* d_in, const int* in_sizes, int n_in,
                              void* d_out, int out_size, void* d_ws, size_t ws_size,
                              hipStream_t stream) {
  const float* zi = (const float*)d_in[0];
  const float* zj = (const float*)d_in[1];
  unsigned short* zbF = (unsigned short*)d_ws;                     // 4 MB
  float* S  = (float*)((char*)d_ws + (size_t)NROWS * DDIM * 2);    // 64 KB
  float* Pp = S + NROWS;                                           // 8 KB
  unsigned int* Cnt = (unsigned int*)(Pp + PREPB);                 // 4 B
  float* out = (float*)d_out;

  hipLaunchKernelGGL(k_prep, dim3(PREPB), dim3(256), 0, stream, zi, zj, zbF, S, Pp, Cnt);
  hipLaunchKernelGGL(k_main, dim3(MAINB), dim3(256), 0, stream, zbF, S, Pp, Cnt, out);
}